// Round 13
// baseline (145.001 us; speedup 1.0000x reference)
//
#include <hip/hip_runtime.h>

typedef __bf16 bf16;
typedef __bf16 bf16x8 __attribute__((ext_vector_type(8)));
typedef float  f32x4  __attribute__((ext_vector_type(4)));
typedef float  f32x16 __attribute__((ext_vector_type(16)));
typedef unsigned int u32x4 __attribute__((ext_vector_type(4)));

#define KK     9
#define KDIM   2304
#define KSTEPS 144           // KDIM / 16  (K-steps of the 32x32x16 MFMA)
#define PXT    32            // pixels per tile (full-K LDS resident)

__device__ __forceinline__ int sreadi(int v) {
    return __builtin_amdgcn_readfirstlane(v);
}

// bf16 pair unpack (uint = 2 packed bf16)
__device__ __forceinline__ float BL(unsigned v) {
    return __builtin_bit_cast(float, v << 16);
}
__device__ __forceinline__ float BH(unsigned v) {
    return __builtin_bit_cast(float, v & 0xffff0000u);
}

// ---------------------------------------------------------------------------
// prep2_k: unchanged (verified rounds 4-12).
// ---------------------------------------------------------------------------
__global__ __launch_bounds__(256) void prep2_k(const float* __restrict__ x,
                                               const float* __restrict__ w,
                                               bf16* __restrict__ xt,
                                               bf16* __restrict__ wq) {
    __shared__ __align__(16) char smem[8 * 2308 * 2];   // 36928 B, aliased
    int bid = blockIdx.x;
    int tid = threadIdx.x;
    if (bid < 1024) {
        float (*tileF)[65] = reinterpret_cast<float(*)[65]>(smem); // 16640 B
        int pt = bid & 63, ct = (bid >> 6) & 3, b = bid >> 8;
        const float* src = x + ((size_t)(b * 256 + ct * 64)) * 4096 + pt * 64;
        int f4 = tid & 15;           // pixel quad
        int cl = tid >> 4;           // channel (base)
        #pragma unroll
        for (int q = 0; q < 4; ++q) {
            int c = q * 16 + cl;
            f32x4 v = *reinterpret_cast<const f32x4*>(src + (size_t)c * 4096 + f4 * 4);
            tileF[f4 * 4 + 0][c] = v[0];
            tileF[f4 * 4 + 1][c] = v[1];
            tileF[f4 * 4 + 2][c] = v[2];
            tileF[f4 * 4 + 3][c] = v[3];
        }
        __syncthreads();
        int j = tid & 7, p0 = tid >> 3;
        bf16* dst = xt + ((size_t)(b * 4096 + pt * 64)) * 256 + ct * 64 + j * 8;
        #pragma unroll
        for (int pp = 0; pp < 2; ++pp) {
            int p = p0 + pp * 32;
            bf16x8 sv;
            #pragma unroll
            for (int k = 0; k < 8; ++k) sv[k] = (bf16)tileF[p][j * 8 + k];
            *reinterpret_cast<bf16x8*>(dst + (size_t)p * 256) = sv;
        }
    } else {
        bf16 (*Wl)[2308] = reinterpret_cast<bf16(*)[2308]>(smem);  // 36928 B
        int wb     = bid - 1024;        // 0..31
        int o_base = wb * 8;
        int m      = o_base >> 5;
        int o31b   = o_base & 31;
        // stage 8 o-rows (coalesced float4) as bf16 in LDS
        #pragma unroll
        for (int pass = 0; pass < 18; ++pass) {
            int i    = pass * 256 + tid;        // < 4608 float4
            int r    = i / 576;
            int col4 = i - r * 576;
            f32x4 v = *reinterpret_cast<const f32x4*>(
                w + (size_t)(o_base + r) * KDIM + col4 * 4);
            Wl[r][col4 * 4 + 0] = (bf16)v[0];
            Wl[r][col4 * 4 + 1] = (bf16)v[1];
            Wl[r][col4 * 4 + 2] = (bf16)v[2];
            Wl[r][col4 * 4 + 3] = (bf16)v[3];
        }
        __syncthreads();
        // compose + store 2304 granules (9 per thread), coalesced in wq
        #pragma unroll
        for (int pass = 0; pass < 9; ++pass) {
            int gid  = pass * 256 + tid;        // < 2304
            int ol   = gid & 7;
            int half = (gid >> 3) & 1;
            int ks   = gid >> 4;                // 0..143
            int kb   = ks * 16 + half * 8;
            int tap  = kb >> 8;
            int cc0  = kb & 255;
            bf16x8 sv;
            #pragma unroll
            for (int j = 0; j < 8; ++j) sv[j] = Wl[ol][(cc0 + j) * 9 + tap];
            size_t g = (size_t)((m * KSTEPS + ks) * 64 + half * 32 + o31b + ol);
            *reinterpret_cast<bf16x8*>(wq + g * 8) = sv;
        }
    }
}

// ---------------------------------------------------------------------------
// deform_gemm_k v13: r12's phase-separated structure (correctness-verified,
// spill-free at 50 us) with the REGISTER CEILING REMOVED:
//   * __launch_bounds__(1024) -- no second arg. Every prior version used
//     (1024,4)/(1024,8) and the allocator pinned VGPR_Count=64 in ALL clean
//     runs, spilling rather than exceeding it (r2/r3/r10/r11 deaths). LDS
//     (147 KB) + grid (256) already force 1 WG/CU, where up to 128 VGPR is
//     legal at 4 waves/SIMD -- occupancy CANNOT degrade from this change.
//   * phase G upgraded with the r11 one-tap-ahead A prefetch (af/an, ~95
//     VGPR peak) that spilled under the 64-cap: hides the per-tap ~300cy
//     L2 A-latency that the rolled loop exposes 18x per WG.
//   * phase S verbatim r12 (unroll 1, one tap's gathers live, TLP-hidden).
// Decisive observables: VGPR_Count (64 -> ~96-128?) and FETCH/WRITE
// (clean = ~10/17 MB; explosion = spill = ceiling immovable).
// Grid 256 (1 WG/CU), 16 waves, 2 sequential 32-px tiles/WG, full-K
// S[9][32x256] = 147 KB. Granule-XOR swizzle (0 conflicts r1-r12),
// kh-epilogue via LDS, XCD banding, 4 barriers/tile: all verbatim r12.
// ---------------------------------------------------------------------------
__global__ __launch_bounds__(1024) void deform_gemm_k(
    const bf16*  __restrict__ xt,
    const float* __restrict__ off,
    const bf16*  __restrict__ wq,
    const float* __restrict__ bias,
    float*       __restrict__ out) {

    __shared__ bf16 S[KK][PXT * 256];   // 9 x 16 KB = 147,456 B

    int tid   = threadIdx.x;
    int wavei = sreadi(tid >> 6);   // 0..15
    int lane  = tid & 63;
    int l32   = lane & 31;
    int half  = lane >> 5;
    int mt    = wavei & 7;          // mtile (32 output channels)
    int kh    = wavei >> 3;         // K-half within each tap

    int bid = blockIdx.x;           // 0..255

    for (int tt = 0; tt < 2; ++tt) {
        int pblk  = ((bid & 7) << 6) | ((bid >> 3) << 1) | tt;  // 0..511
        int pix0  = pblk * PXT;
        int b     = pix0 >> 12;                  // tile-uniform batch
        int pimgb = pix0 & 4095;
        int obase = b * 73728;

        int n    = wavei * 2 + half;             // this lane's S row 0..31
        int pimg = pimgb + n;
        int py_i = pimg >> 6, px_i = pimg & 63;
        const char* xb = (const char*)xt + ((size_t)b << 21) + l32 * 16;

        // ====== phase S: sample all 9 taps, loop NOT unrolled ======
        // (unroll 1 = the register-pressure fence: one tap's gathers live)
        #pragma unroll 1
        for (int tap = 0; tap < KK; ++tap) {
            int ty = tap / 3 - 1;
            int tx = tap % 3 - 1;
            float oy = off[obase + (2 * tap) * 4096 + pimg];
            float ox = off[obase + (2 * tap + 1) * 4096 + pimg];
            float py = (float)(py_i + ty) + oy;
            float px = (float)(px_i + tx) + ox;
            float fy = floorf(py), fx = floorf(px);
            int   y0 = (int)fy,    x0 = (int)fx;
            float wy1 = py - fy, wx1 = px - fx;
            float wy0 = 1.f - wy1, wx0 = 1.f - wx1;
            wy0 = ((unsigned)y0       < 64u) ? wy0 : 0.f;
            wy1 = ((unsigned)(y0 + 1) < 64u) ? wy1 : 0.f;
            wx0 = ((unsigned)x0       < 64u) ? wx0 : 0.f;
            wx1 = ((unsigned)(x0 + 1) < 64u) ? wx1 : 0.f;
            int yc0 = min(max(y0, 0), 63), yc1 = min(max(y0 + 1, 0), 63);
            int xc0 = min(max(x0, 0), 63), xc1 = min(max(x0 + 1, 0), 63);
            unsigned u0 = (unsigned)(yc0 * 64 + xc0) * 512u;
            unsigned u1 = (unsigned)(yc0 * 64 + xc1) * 512u;
            unsigned u2 = (unsigned)(yc1 * 64 + xc0) * 512u;
            unsigned u3 = (unsigned)(yc1 * 64 + xc1) * 512u;
            float w0 = wy0 * wx0, w1 = wy0 * wx1;
            float w2 = wy1 * wx0, w3 = wy1 * wx1;
            u32x4 g0 = *(const u32x4*)(xb + u0);
            u32x4 g1 = *(const u32x4*)(xb + u1);
            u32x4 g2 = *(const u32x4*)(xb + u2);
            u32x4 g3 = *(const u32x4*)(xb + u3);
            bf16x8 sv;
            #pragma unroll
            for (int q = 0; q < 4; ++q) {
                float lo = fmaf(w0, BL(g0[q]), fmaf(w1, BL(g1[q]),
                           fmaf(w2, BL(g2[q]),      w3 * BL(g3[q]))));
                float hi = fmaf(w0, BH(g0[q]), fmaf(w1, BH(g1[q]),
                           fmaf(w2, BH(g2[q]),      w3 * BH(g3[q]))));
                sv[q * 2]     = (bf16)lo;
                sv[q * 2 + 1] = (bf16)hi;
            }
            int gsw = l32 ^ n;                 // granule-XOR swizzle
            *reinterpret_cast<bf16x8*>(&S[tap][0] + n * 256 + gsw * 8) = sv;
        }

        __syncthreads();   // S complete

        // ====== phase G: streaming GEMM, 1-tap-ahead A prefetch ======
        f32x16 acc;
        #pragma unroll
        for (int r = 0; r < 16; ++r) acc[r] = 0.f;

        const bf16* apb = wq +
            ((size_t)(((mt * KSTEPS) + kh * 8) * 64 + lane)) * 8;
        bf16x8 af[8];
        #pragma unroll
        for (int s = 0; s < 8; ++s)
            af[s] = *reinterpret_cast<const bf16x8*>(apb + (size_t)s * 512);

        #pragma unroll 1
        for (int tap = 0; tap < KK; ++tap) {
            bf16x8 an[8];
            if (tap < KK - 1) {
                const bf16* apn = apb + (size_t)(tap + 1) * (16 * 64 * 8);
                #pragma unroll
                for (int s = 0; s < 8; ++s)
                    an[s] = *reinterpret_cast<const bf16x8*>(apn + (size_t)s * 512);
            }
            const bf16* Sr = &S[tap][0];
            #pragma unroll
            for (int s = 0; s < 8; ++s) {
                int g  = (kh * 8 + s) * 2 + half;   // 16B granule
                int gs = g ^ l32;                   // row = l32
                bf16x8 bv = *reinterpret_cast<const bf16x8*>(Sr + l32 * 256 + gs * 8);
                acc = __builtin_amdgcn_mfma_f32_32x32x16_bf16(af[s], bv, acc, 0, 0, 0);
            }
            if (tap < KK - 1) {
                #pragma unroll
                for (int s = 0; s < 8; ++s) af[s] = an[s];
            }
        }

        __syncthreads();   // all S reads done; S reusable as Sf

        // ============ epilogue (verbatim r12): kh-reduce + store ==========
        float* Sf = reinterpret_cast<float*>(&S[0][0]);   // 8192 f32 = 32 KB
        if (kh == 1) {
            int wb = (wavei - 8) * 64 + lane;
            #pragma unroll
            for (int r = 0; r < 16; ++r)
                Sf[r * 512 + wb] = acc[r];   // lane-major: conflict-free b32
        }
        __syncthreads();
        if (kh == 0) {
            // C/D layout: col = lane&31, row = (r&3)+8*(r>>2)+4*half
            int wb   = wavei * 64 + lane;
            int m    = mt * 32;              // mt == wavei here (kh == 0)
            int pimo = pimgb + l32;
            float* op = out + ((size_t)(b * 256 + m)) * 4096 + pimo;
            #pragma unroll
            for (int r = 0; r < 16; ++r) {
                int row = (r & 3) + 8 * (r >> 2) + half * 4;
                float v = acc[r] + Sf[r * 512 + wb] + bias[m + row];
                op[(size_t)row * 4096] = v;
            }
        }
        __syncthreads();   // Sf reads done before next tile's sampling
    }
}

// ---------------------------------------------------------------------------
extern "C" void kernel_launch(void* const* d_in, const int* in_sizes, int n_in,
                              void* d_out, int out_size, void* d_ws, size_t ws_size,
                              hipStream_t stream) {
    const float* x    = (const float*)d_in[0];   // [4,256,64,64]
    const float* off  = (const float*)d_in[1];   // [4,18,64,64]
    const float* w    = (const float*)d_in[2];   // [256,256,3,3]
    const float* bias = (const float*)d_in[3];   // [256]
    float* out = (float*)d_out;                  // [4,256,64,64]

    bf16* wq = (bf16*)d_ws;                               // 1,179,648 B
    bf16* xt = (bf16*)((char*)d_ws + (size_t)589824 * 2); // 8,388,608 B

    prep2_k<<<1056, 256, 0, stream>>>(x, w, xt, wq);
    deform_gemm_k<<<256, 1024, 0, stream>>>(xt, off, wq, bias, out);
}

// Round 14
// 114.198 us; speedup vs baseline: 1.2697x; 1.2697x over previous
//
#include <hip/hip_runtime.h>

typedef __bf16 bf16;
typedef __bf16 bf16x4 __attribute__((ext_vector_type(4)));
typedef __bf16 bf16x8 __attribute__((ext_vector_type(8)));
typedef float  f32x4  __attribute__((ext_vector_type(4)));
typedef float  f32x16 __attribute__((ext_vector_type(16)));
typedef unsigned int u32x4 __attribute__((ext_vector_type(4)));

#define KK     9
#define KDIM   2304
#define KSTEPS 144           // KDIM / 16  (K-steps of the 32x32x16 MFMA)
#define PXW    64            // pixels per WG

__device__ __forceinline__ int sreadi(int v) {
    return __builtin_amdgcn_readfirstlane(v);
}

// bf16 pair unpack (uint = 2 packed bf16)
__device__ __forceinline__ float BL(unsigned v) {
    return __builtin_bit_cast(float, v << 16);
}
__device__ __forceinline__ float BH(unsigned v) {
    return __builtin_bit_cast(float, v & 0xffff0000u);
}

// ---------------------------------------------------------------------------
// prep2_k: unchanged (verified rounds 4-13).
// ---------------------------------------------------------------------------
__global__ __launch_bounds__(256) void prep2_k(const float* __restrict__ x,
                                               const float* __restrict__ w,
                                               bf16* __restrict__ xt,
                                               bf16* __restrict__ wq) {
    __shared__ __align__(16) char smem[8 * 2308 * 2];   // 36928 B, aliased
    int bid = blockIdx.x;
    int tid = threadIdx.x;
    if (bid < 1024) {
        float (*tileF)[65] = reinterpret_cast<float(*)[65]>(smem); // 16640 B
        int pt = bid & 63, ct = (bid >> 6) & 3, b = bid >> 8;
        const float* src = x + ((size_t)(b * 256 + ct * 64)) * 4096 + pt * 64;
        int f4 = tid & 15;           // pixel quad
        int cl = tid >> 4;           // channel (base)
        #pragma unroll
        for (int q = 0; q < 4; ++q) {
            int c = q * 16 + cl;
            f32x4 v = *reinterpret_cast<const f32x4*>(src + (size_t)c * 4096 + f4 * 4);
            tileF[f4 * 4 + 0][c] = v[0];
            tileF[f4 * 4 + 1][c] = v[1];
            tileF[f4 * 4 + 2][c] = v[2];
            tileF[f4 * 4 + 3][c] = v[3];
        }
        __syncthreads();
        int j = tid & 7, p0 = tid >> 3;
        bf16* dst = xt + ((size_t)(b * 4096 + pt * 64)) * 256 + ct * 64 + j * 8;
        #pragma unroll
        for (int pp = 0; pp < 2; ++pp) {
            int p = p0 + pp * 32;
            bf16x8 sv;
            #pragma unroll
            for (int k = 0; k < 8; ++k) sv[k] = (bf16)tileF[p][j * 8 + k];
            *reinterpret_cast<bf16x8*>(dst + (size_t)p * 256) = sv;
        }
    } else {
        bf16 (*Wl)[2308] = reinterpret_cast<bf16(*)[2308]>(smem);  // 36928 B
        int wb     = bid - 1024;        // 0..31
        int o_base = wb * 8;
        int m      = o_base >> 5;
        int o31b   = o_base & 31;
        // stage 8 o-rows (coalesced float4) as bf16 in LDS
        #pragma unroll
        for (int pass = 0; pass < 18; ++pass) {
            int i    = pass * 256 + tid;        // < 4608 float4
            int r    = i / 576;
            int col4 = i - r * 576;
            f32x4 v = *reinterpret_cast<const f32x4*>(
                w + (size_t)(o_base + r) * KDIM + col4 * 4);
            Wl[r][col4 * 4 + 0] = (bf16)v[0];
            Wl[r][col4 * 4 + 1] = (bf16)v[1];
            Wl[r][col4 * 4 + 2] = (bf16)v[2];
            Wl[r][col4 * 4 + 3] = (bf16)v[3];
        }
        __syncthreads();
        // compose + store 2304 granules (9 per thread), coalesced in wq
        #pragma unroll
        for (int pass = 0; pass < 9; ++pass) {
            int gid  = pass * 256 + tid;        // < 2304
            int ol   = gid & 7;
            int half = (gid >> 3) & 1;
            int ks   = gid >> 4;                // 0..143
            int kb   = ks * 16 + half * 8;
            int tap  = kb >> 8;
            int cc0  = kb & 255;
            bf16x8 sv;
            #pragma unroll
            for (int j = 0; j < 8; ++j) sv[j] = Wl[ol][(cc0 + j) * 9 + tap];
            size_t g = (size_t)((m * KSTEPS + ks) * 64 + half * 32 + o31b + ol);
            *reinterpret_cast<bf16x8*>(wq + g * 8) = sv;
        }
    }
}

// ---------------------------------------------------------------------------
// deform_gemm_k: VERBATIM round-6 version -- the session's best verified
// kernel (gemm 46.4 us, total 112.3 us; FETCH 9.7 MB, WRITE 16.4 MB,
// 0 bank conflicts, no spill). Restored per round-12 pre-commitment after
// r13's launch-bounds experiment refuted the last open theory (VGPR stayed
// 64; af/an prefetch spilled: 5th spill death with identical signature).
// Structural-floor argument: four verified schedules (lockstep 2-buf 50.8,
// lane-split 49.9, PXW=64 46.4, ring3 <=44.9, phase-separated 49.8) land
// within +-10% with NO saturated pipe (MfmaUtil ~16%, VALU ~32%, HBM ~7%).
// The binding constraint is the triangle: (a) gather/A latency needs
// register-held cross-phase state; (b) the allocator's 64-VGPR wall forbids
// it (spills instead, 5/5 attempts); (c) __syncthreads' vmcnt(0) drain
// forbids LDS-held prefetch across barriers. All exits measured.
//
// Geometry: PXW=64, grid 256 (1 WG/CU), 16 waves; wave (mt=wavei&7,
// kh=wavei>>3) = 32 out-chans x 64 px (2 ntiles, acc = 2 x f32x16),
// K-half kh per tap. Per tap: half-wave fills rows n0/n1 (two r5-style
// bodies: 4 x dwordx4 corner gathers, blend, one swizzled b128 ds_write);
// 8 A-frags prefetched between bodies (latency drains at the barrier's
// vmcnt(0)); ONE barrier per tap; double-buffered S; off prefetched one
// tap ahead across the GEMM. Granule-XOR swizzle (0 conflicts r1-r12);
// kh-epilogue reduction via LDS; XCD banding; tap rotation.
// ---------------------------------------------------------------------------
__global__ __launch_bounds__(1024, 4) void deform_gemm_k(
    const bf16*  __restrict__ xt,
    const float* __restrict__ off,
    const bf16*  __restrict__ wq,
    const float* __restrict__ bias,
    float*       __restrict__ out) {

    __shared__ bf16 S[2][PXW * 256];   // 2 x 32 KB, swizzled 16B granules

    int tid   = threadIdx.x;
    int wavei = sreadi(tid >> 6);   // 0..15
    int lane  = tid & 63;
    int l32   = lane & 31;
    int half  = lane >> 5;
    int mt    = wavei & 7;          // mtile (32 output channels)
    int kh    = wavei >> 3;         // K-half within each tap

    int bid   = blockIdx.x;                      // 0..255
    int pb    = ((bid & 7) << 5) | (bid >> 3);   // XCD-band pixel-block
    int pix0  = pb * PXW;
    int b     = pix0 >> 12;                      // WG-uniform batch
    int pimgb = pix0 & 4095;
    int obase = b * 73728;                       // base into off[]
    int rot   = (bid >> 3) & 7;                  // tap-phase desync across CUs

    // sampling geometry: this lane serves rows n0, n1
    int n0    = wavei * 4 + half * 2;
    int n1    = n0 + 1;
    int pimg0 = pimgb + n0;
    int pimg1 = pimgb + n1;
    const char* xb = (const char*)xt + ((size_t)b << 21) + l32 * 16;

    f32x16 acc0, acc1;
    #pragma unroll
    for (int r = 0; r < 16; ++r) { acc0[r] = 0.f; acc1[r] = 0.f; }

    // one sampling body: row n / pixel pimg with offsets (oy, ox)
    auto body = [&](int n, int pimg, float oy, float ox, int ty, int tx,
                    bf16* Sw) {
        float py = (float)((pimg >> 6) + ty) + oy;
        float px = (float)((pimg & 63) + tx) + ox;
        float fy = floorf(py), fx = floorf(px);
        int   y0 = (int)fy,    x0 = (int)fx;
        float wy1 = py - fy, wx1 = px - fx;
        float wy0 = 1.f - wy1, wx0 = 1.f - wx1;
        wy0 = ((unsigned)y0       < 64u) ? wy0 : 0.f;
        wy1 = ((unsigned)(y0 + 1) < 64u) ? wy1 : 0.f;
        wx0 = ((unsigned)x0       < 64u) ? wx0 : 0.f;
        wx1 = ((unsigned)(x0 + 1) < 64u) ? wx1 : 0.f;
        int yc0 = min(max(y0, 0), 63), yc1 = min(max(y0 + 1, 0), 63);
        int xc0 = min(max(x0, 0), 63), xc1 = min(max(x0 + 1, 0), 63);
        unsigned u0 = (unsigned)(yc0 * 64 + xc0) * 512u;
        unsigned u1 = (unsigned)(yc0 * 64 + xc1) * 512u;
        unsigned u2 = (unsigned)(yc1 * 64 + xc0) * 512u;
        unsigned u3 = (unsigned)(yc1 * 64 + xc1) * 512u;
        float w0 = wy0 * wx0, w1 = wy0 * wx1;
        float w2 = wy1 * wx0, w3 = wy1 * wx1;
        u32x4 g0 = *(const u32x4*)(xb + u0);
        u32x4 g1 = *(const u32x4*)(xb + u1);
        u32x4 g2 = *(const u32x4*)(xb + u2);
        u32x4 g3 = *(const u32x4*)(xb + u3);
        bf16x8 sv;
        #pragma unroll
        for (int q = 0; q < 4; ++q) {
            float lo = fmaf(w0, BL(g0[q]), fmaf(w1, BL(g1[q]),
                       fmaf(w2, BL(g2[q]),      w3 * BL(g3[q]))));
            float hi = fmaf(w0, BH(g0[q]), fmaf(w1, BH(g1[q]),
                       fmaf(w2, BH(g2[q]),      w3 * BH(g3[q]))));
            sv[q * 2]     = (bf16)lo;
            sv[q * 2 + 1] = (bf16)hi;
        }
        int gsw = l32 ^ (n & 31);              // granule-XOR swizzle
        *reinterpret_cast<bf16x8*>(Sw + n * 256 + gsw * 8) = sv;
    };

    // off prefetch for t=0
    float oy0 = off[obase + (2 * rot)     * 4096 + pimg0];
    float ox0 = off[obase + (2 * rot + 1) * 4096 + pimg0];
    float oy1 = off[obase + (2 * rot)     * 4096 + pimg1];
    float ox1 = off[obase + (2 * rot + 1) * 4096 + pimg1];

    for (int t = 0; t < KK; ++t) {
        int tap = t + rot; if (tap >= KK) tap -= KK;
        int ty = tap / 3 - 1;
        int tx = tap % 3 - 1;
        bf16* Sw = &S[t & 1][0];

        // ---- sampling body 0 ----
        body(n0, pimg0, oy0, ox0, ty, tx, Sw);

        // ---- A-frag prefetch (8): issued here so body-1's work + the
        //      barrier drain cover their L2 latency ----
        const bf16* ap0 = wq +
            ((size_t)(((mt * KSTEPS) + tap * 16 + kh * 8) * 64 + lane)) * 8;
        bf16x8 af[8];
        #pragma unroll
        for (int s = 0; s < 8; ++s)
            af[s] = *reinterpret_cast<const bf16x8*>(ap0 + (size_t)s * 512);

        // ---- sampling body 1 ----
        body(n1, pimg1, oy1, ox1, ty, tx, Sw);

        __syncthreads();

        // ---- off prefetch for tap t+1 (flies across the GEMM) ----
        if (t < KK - 1) {
            int tn = tap + 1; if (tn >= KK) tn = 0;
            oy0 = off[obase + (2 * tn)     * 4096 + pimg0];
            ox0 = off[obase + (2 * tn + 1) * 4096 + pimg0];
            oy1 = off[obase + (2 * tn)     * 4096 + pimg1];
            ox1 = off[obase + (2 * tn + 1) * 4096 + pimg1];
        }

        // ---- GEMM: this wave's K-half x 64 px (2 ntiles) ----
        const bf16* Sr = Sw;
        #pragma unroll
        for (int s = 0; s < 8; ++s) {
            int g  = (kh * 8 + s) * 2 + half;   // 16B granule (cin base >> 3)
            int gs = g ^ l32;                   // row & 31 == l32 for both nt
            bf16x8 b0 = *reinterpret_cast<const bf16x8*>(Sr + l32 * 256 + gs * 8);
            bf16x8 b1 = *reinterpret_cast<const bf16x8*>(Sr + (32 + l32) * 256 + gs * 8);
            acc0 = __builtin_amdgcn_mfma_f32_32x32x16_bf16(af[s], b0, acc0, 0, 0, 0);
            acc1 = __builtin_amdgcn_mfma_f32_32x32x16_bf16(af[s], b1, acc1, 0, 0, 0);
        }
        // next tap writes the OTHER buffer; re-write of this buffer (t+2)
        // is ordered behind barrier t+1.
    }

    // ---- epilogue: sum the two K-halves through LDS, then store ----
    __syncthreads();                 // all GEMM reads of S done
    float* Sf = reinterpret_cast<float*>(&S[0][0]);   // 16384 f32 = 64 KB
    if (kh == 1) {
        #pragma unroll
        for (int r = 0; r < 16; ++r) {
            Sf[((mt * 2 + 0) * 16 + r) * 64 + lane] = acc0[r];
            Sf[((mt * 2 + 1) * 16 + r) * 64 + lane] = acc1[r];
        }
    }
    __syncthreads();
    if (kh == 0) {
        // C/D layout (32x32x16): col = lane&31, row = (r&3)+8*(r>>2)+4*half
        int m = mt * 32;
        #pragma unroll
        for (int nt = 0; nt < 2; ++nt) {
            int px = pimgb + nt * 32 + l32;
            float* op = out + ((size_t)(b * 256 + m)) * 4096 + px;
            #pragma unroll
            for (int r = 0; r < 16; ++r) {
                int row = (r & 3) + 8 * (r >> 2) + half * 4;
                float a = (nt == 0) ? acc0[r] : acc1[r];
                float v = a + Sf[((mt * 2 + nt) * 16 + r) * 64 + lane]
                            + bias[m + row];
                op[(size_t)row * 4096] = v;
            }
        }
    }
}

// ---------------------------------------------------------------------------
extern "C" void kernel_launch(void* const* d_in, const int* in_sizes, int n_in,
                              void* d_out, int out_size, void* d_ws, size_t ws_size,
                              hipStream_t stream) {
    const float* x    = (const float*)d_in[0];   // [4,256,64,64]
    const float* off  = (const float*)d_in[1];   // [4,18,64,64]
    const float* w    = (const float*)d_in[2];   // [256,256,3,3]
    const float* bias = (const float*)d_in[3];   // [256]
    float* out = (float*)d_out;                  // [4,256,64,64]

    bf16* wq = (bf16*)d_ws;                               // 1,179,648 B
    bf16* xt = (bf16*)((char*)d_ws + (size_t)589824 * 2); // 8,388,608 B

    prep2_k<<<1056, 256, 0, stream>>>(x, w, xt, wq);
    deform_gemm_k<<<256, 1024, 0, stream>>>(xt, off, wq, bias, out);
}